// Round 5
// baseline (35.355 us; speedup 1.0000x reference)
//
#include <hip/hip_runtime.h>

// out[b,o] = sum_{i,n} (Ps*tanh(k*(x + Ec*bm)) + bias) * coef
// bm = 1 - 0.4*(1 - sigmoid(10*(x_b - x_{b-1}))) * sigmoid(10*(-x - Ec))
// (switch_up cancels: target = 1 - 2*switch_lo)
//
// R5: R1/R2/R4 all ~28us despite occupancy/LDS/ILP changes => structure-
// independent. Cycle accounting: 28us = 129 cyc/term; body = 14 cyc full-
// rate + 4 trans => trans cost ~28 cyc/wave64 each (NOT the 8-cyc quarter-
// rate model). Kernel is transcendental-throughput-bound.
// Fix: zero-trans main loop. tanh via Pade [5/4] (continued-fraction
// truncation, exact integer coeffs, |err|<5e-3 on |w|<=4.6, clamped):
//   tanh(w) ~= w*(945+105w^2+w^4) / (945+420w^2+15w^4)
// sigmoid(u) = 0.5+0.5*tanh(u/2) folded into precomputed constants.
// Reciprocal via bit-trick + 2 Newton (rel err ~1e-4). ~34 full-rate
// ops/term = 68 cyc => predicted ~15us.

#define GATE_C 14.426950408889634f   // 10*log2(e), prologue only

constexpr int B = 512, I = 128, O = 64, NB = 8, BT = 16;

__device__ __forceinline__ float fast_rcp(float d) {
  // d > 0 (den = 945+420w^2+15w^4 >= 945). ~10% -> 1% -> 1e-4 rel.
  float y = __int_as_float(0x7EF127EA - __float_as_int(d));
  y = y * fmaf(-d, y, 2.f);
  y = y * fmaf(-d, y, 2.f);
  return y;
}

__global__ __launch_bounds__(256, 4) void fe_main(
    const float* __restrict__ x, const float* __restrict__ k,
    const float* __restrict__ Ec, const float* __restrict__ Ps,
    const float* __restrict__ bias, const float* __restrict__ coef,
    float* __restrict__ out)
{
  __shared__ float4 p_lds[I * NB];        // {Ec, -5*Ec, k, Ps*coef} per [i][n]
  __shared__ float2 xc_lds[BT][I + 1];    // {x, ch = -0.2*sigmoid(-10*dx)}
  __shared__ float red[4];

  const int tid = threadIdx.x;
  const int o  = blockIdx.y;
  const int b0 = blockIdx.x * BT;

  // ---- stage params for this o; base[o] = sum bias*coef ----
  float pbase = 0.f;
  for (int e = tid; e < I * NB; e += 256) {
    const int i = e >> 3, n = e & 7;
    const int g = (i * O + o) * NB + n;
    const float E = Ec[g], K = k[g], P = Ps[g], C = coef[g], Bs = bias[g];
    p_lds[e] = make_float4(E, -5.f * E, K, P * C);
    pbase += Bs * C;
  }

  // ---- stage {x, ch} (hw trans OK here: only B*I evals) ----
  for (int e = tid; e < BT * I; e += 256) {
    const int bl = e >> 7, i = e & 127;
    const int bg = b0 + bl;
    const float xv = x[bg * I + i];
    const float pv = (bg == 0) ? 0.f : x[(bg - 1) * I + i];
    // ch = 0.5*c = -0.2 * sigmoid(-10*(x - prev))
    const float ch = -0.2f * __builtin_amdgcn_rcpf(
        1.f + __builtin_amdgcn_exp2f(GATE_C * (xv - pv)));
    xc_lds[bl][i] = make_float2(xv, ch);
  }

  // base[o]: full-wave butterfly, one partial per wave
  #pragma unroll
  for (int m = 1; m < 64; m <<= 1) pbase += __shfl_xor(pbase, m);
  if ((tid & 63) == 0) red[tid >> 6] = pbase;
  __syncthreads();

  // ---- main loop: thread = (bl, ih, n); zero transcendentals ----
  const int bl = tid >> 4, ih = (tid >> 3) & 1, n = tid & 7;
  const float4* __restrict__ prow = p_lds + (ih * 64) * 8 + n;
  const float2* __restrict__ xrow = &xc_lds[bl][ih * 64];

  float acc = 0.f;
  #pragma unroll 4
  for (int it = 0; it < 64; ++it) {
    const float2 xc = xrow[it];
    const float4 p  = prow[it * 8];
    const float xv = xc.x, ch = xc.y;
    const float bh = 1.f + ch;

    // gate: sg = sigmoid(-10(x+Ec)) = 0.5 + 0.5*tanh(wg), wg = -5(x+Ec)
    float wg = fmaf(xv, -5.f, p.y);
    wg = fminf(fmaxf(wg, -4.6f), 4.6f);
    const float g2 = wg * wg;
    const float gnum = fmaf(g2 + 105.f, g2, 945.f);
    const float gden = fmaf(fmaf(g2, 15.f, 420.f), g2, 945.f);
    const float tg = wg * gnum * fast_rcp(gden);   // tanh(wg)
    // bm = 1 + c*sg = (1+ch) + ch*tanh(wg)
    const float bm = fmaf(ch, tg, bh);

    // basis: tanh(k * (x + Ec*bm)), Pade + clamp
    const float inner = fmaf(p.x, bm, xv);
    float v = p.z * inner;
    v = fminf(fmaxf(v, -4.6f), 4.6f);
    const float v2 = v * v;
    const float tnum = fmaf(v2 + 105.f, v2, 945.f);
    const float tden = fmaf(fmaf(v2, 15.f, 420.f), v2, 945.f);
    acc = fmaf(p.w * v, tnum * fast_rcp(tden), acc);  // += pc*tanh(v)
  }

  // reduce over n (1,2,4) then ih (8)
  acc += __shfl_xor(acc, 1);
  acc += __shfl_xor(acc, 2);
  acc += __shfl_xor(acc, 4);
  acc += __shfl_xor(acc, 8);

  if ((tid & 15) == 0) {
    const float base = red[0] + red[1] + red[2] + red[3];
    out[(b0 + bl) * O + o] = base + acc;
  }
}

extern "C" void kernel_launch(void* const* d_in, const int* in_sizes, int n_in,
                              void* d_out, int out_size, void* d_ws, size_t ws_size,
                              hipStream_t stream) {
  const float* x    = (const float*)d_in[0];
  const float* k    = (const float*)d_in[1];
  const float* Ec   = (const float*)d_in[2];
  const float* Ps   = (const float*)d_in[3];
  const float* bias = (const float*)d_in[4];
  const float* coef = (const float*)d_in[5];
  float* out = (float*)d_out;

  dim3 grid(B / BT, O);   // 32 batch tiles x 64 output channels
  fe_main<<<grid, 256, 0, stream>>>(x, k, Ec, Ps, bias, coef, out);
}

// Round 6
// 31.484 us; speedup vs baseline: 1.1230x; 1.1230x over previous
//
#include <hip/hip_runtime.h>

// out[b,o] = sum_{i,n} (Ps*tanh(k*(x + Ec*bm)) + bias) * coef
// bm = 1 + ch*(1+tg), ch = -0.2*sigmoid(-10*(x-prev)), tg = tanh(-5*(x+Ec))
// (switch_up cancels; sigmoid written via tanh)
//
// R6: R5 showed VALUBusy 70% => VALU-issue-count bound (hw trans ~16cyc =>
// R1 and R5 nearly tied at 78 vs 66 issue-cyc/term; all structural changes
// neutral). Fix: packed f32 (v_pk_fma_f32 etc. via <2 x float>) pairing
// adjacent i's => ~17 issues/term. Output-clamp (med3 to +-1) replaces
// input clamps (Pade[5/4] ratio stays in [0.999,1.17] beyond |w|=3.5).
// Conflict-free LDS map: n=tid&7, bl=(tid>>3)&7, iq=waveid => 8 distinct
// addrs on 8 distinct bank-quads for both reads. BT=8 => 25KB LDS,
// 6 blocks/CU. Predicted 11-14us, VALUBusy 80%+.

#define GATE_C 14.426950408889634f   // 10*log2(e), prologue only

typedef float f32x2 __attribute__((ext_vector_type(2)));
typedef float f32x4 __attribute__((ext_vector_type(4)));
typedef int   i32x2 __attribute__((ext_vector_type(2)));

constexpr int B = 512, I = 128, O = 64, NB = 8, BT = 8, IP = I / 2;

__device__ __forceinline__ f32x2 pk_seed(f32x2 d) {
  i32x2 yi = (i32x2)(0x7EF127EA) - __builtin_bit_cast(i32x2, d);
  return __builtin_bit_cast(f32x2, yi);
}
__device__ __forceinline__ f32x2 pk_newton(f32x2 y, f32x2 d) {
  return y * __builtin_elementwise_fma(-d, y, (f32x2)(2.f));
}
__device__ __forceinline__ f32x2 pk_clamp1(f32x2 t) {   // med3 to [-1,1]
  t.x = fminf(fmaxf(t.x, -1.f), 1.f);
  t.y = fminf(fmaxf(t.y, -1.f), 1.f);
  return t;
}

__global__ __launch_bounds__(256, 6) void fe_main(
    const float* __restrict__ x, const float* __restrict__ k,
    const float* __restrict__ Ec, const float* __restrict__ Ps,
    const float* __restrict__ bias, const float* __restrict__ coef,
    float* __restrict__ out)
{
  __shared__ f32x4 pA[IP][NB];        // {Ec_i, Ec_j, -5Ec_i, -5Ec_j}
  __shared__ f32x4 pB[IP][NB];        // {k_i, k_j, Ps*coef_i, Ps*coef_j}
  __shared__ f32x4 xcp[BT][IP + 1];   // {x_i, x_j, ch_i, ch_j}; pad
  __shared__ float racc[4][BT];
  __shared__ float red[4];

  const int tid = threadIdx.x;
  const int o  = blockIdx.y;
  const int b0 = blockIdx.x * BT;

  // ---- stage params for i-pairs; base[o] = sum bias*coef partial ----
  float pbase = 0.f;
  for (int e = tid; e < IP * NB; e += 256) {
    const int ip = e >> 3, nn = e & 7;
    const int g0 = ((2 * ip) * O + o) * NB + nn, g1 = g0 + O * NB;
    const float E0 = Ec[g0], E1 = Ec[g1];
    const float K0 = k[g0],  K1 = k[g1];
    const float pc0 = Ps[g0] * coef[g0], pc1 = Ps[g1] * coef[g1];
    pA[ip][nn] = (f32x4){E0, E1, -5.f * E0, -5.f * E1};
    pB[ip][nn] = (f32x4){K0, K1, pc0, pc1};
    pbase += fmaf(bias[g0], coef[g0], bias[g1] * coef[g1]);
  }

  // ---- stage {x, ch} pairs (hw trans fine: prologue only) ----
  const float2* __restrict__ x2p = (const float2*)x;
  for (int e = tid; e < BT * IP; e += 256) {
    const int bl = e >> 6, ip = e & 63;
    const int bg = b0 + bl;
    const float2 xv = x2p[bg * IP + ip];
    float2 pv = make_float2(0.f, 0.f);
    if (bg != 0) pv = x2p[(bg - 1) * IP + ip];
    const float ch0 = -0.2f * __builtin_amdgcn_rcpf(
        1.f + __builtin_amdgcn_exp2f(GATE_C * (xv.x - pv.x)));
    const float ch1 = -0.2f * __builtin_amdgcn_rcpf(
        1.f + __builtin_amdgcn_exp2f(GATE_C * (xv.y - pv.y)));
    xcp[bl][ip] = (f32x4){xv.x, xv.y, ch0, ch1};
  }

  // base[o]: full-wave butterfly, one partial per wave
  #pragma unroll
  for (int m = 1; m < 64; m <<= 1) pbase += __shfl_xor(pbase, m);
  if ((tid & 63) == 0) red[tid >> 6] = pbase;
  __syncthreads();

  // ---- main loop: thread = (n, bl, iq=wave); 16 i-pairs each ----
  const int n  = tid & 7;
  const int bl = (tid >> 3) & 7;
  const int iq = tid >> 6;            // == wave id: conflict-free reads
  const f32x4* __restrict__ pArow = &pA[iq * 16][n];
  const f32x4* __restrict__ pBrow = &pB[iq * 16][n];
  const f32x4* __restrict__ xrow  = &xcp[bl][iq * 16];

  f32x2 acc = (f32x2)(0.f);
  #pragma unroll
  for (int it = 0; it < 16; ++it) {
    const f32x4 xc = xrow[it];
    const f32x4 a  = pArow[it * 8];
    const f32x4 bb = pBrow[it * 8];
    const f32x2 x2 = xc.lo, ch2 = xc.hi;
    const f32x2 ec2 = a.lo, eg2 = a.hi;
    const f32x2 kv2 = bb.lo, pc2 = bb.hi;

    // gate tanh: wg = -5x - 5Ec; Pade[5/4] + output clamp
    const f32x2 wg = __builtin_elementwise_fma(x2, (f32x2)(-5.f), eg2);
    const f32x2 g2 = wg * wg;
    const f32x2 gnum = __builtin_elementwise_fma(g2 + 105.f, g2, (f32x2)(945.f));
    const f32x2 gden = __builtin_elementwise_fma(
        __builtin_elementwise_fma(g2, (f32x2)(15.f), (f32x2)(420.f)), g2, (f32x2)(945.f));
    const f32x2 rg = pk_newton(pk_seed(gden), gden);          // 1 Newton
    const f32x2 tg = pk_clamp1(wg * gnum * rg);

    // bm = 1 + ch*(1+tg); inner = x + Ec*bm; v = k*inner
    const f32x2 bm = __builtin_elementwise_fma(ch2, tg + 1.f, (f32x2)(1.f));
    const f32x2 inner = __builtin_elementwise_fma(ec2, bm, x2);
    const f32x2 v  = kv2 * inner;
    const f32x2 v2 = v * v;
    const f32x2 tnum = __builtin_elementwise_fma(v2 + 105.f, v2, (f32x2)(945.f));
    const f32x2 tden = __builtin_elementwise_fma(
        __builtin_elementwise_fma(v2, (f32x2)(15.f), (f32x2)(420.f)), v2, (f32x2)(945.f));
    f32x2 rt = pk_newton(pk_seed(tden), tden);
    rt = pk_newton(rt, tden);                                 // 2 Newton
    const f32x2 t = pk_clamp1(v * tnum * rt);

    acc = __builtin_elementwise_fma(pc2, t, acc);
  }

  // reduce: pair, then n-lanes (1,2,4); stash per (iq, bl)
  float s = acc.x + acc.y;
  s += __shfl_xor(s, 1);
  s += __shfl_xor(s, 2);
  s += __shfl_xor(s, 4);
  if (n == 0) racc[iq][bl] = s;
  __syncthreads();

  // final: 8 outputs per block
  if (tid < BT) {
    const float r = racc[0][tid] + racc[1][tid] + racc[2][tid] + racc[3][tid];
    const float base = red[0] + red[1] + red[2] + red[3];
    out[(b0 + tid) * O + o] = r + base;
  }
}

extern "C" void kernel_launch(void* const* d_in, const int* in_sizes, int n_in,
                              void* d_out, int out_size, void* d_ws, size_t ws_size,
                              hipStream_t stream) {
  const float* x    = (const float*)d_in[0];
  const float* k    = (const float*)d_in[1];
  const float* Ec   = (const float*)d_in[2];
  const float* Ps   = (const float*)d_in[3];
  const float* bias = (const float*)d_in[4];
  const float* coef = (const float*)d_in[5];
  float* out = (float*)d_out;

  dim3 grid(B / BT, O);   // 64 batch tiles x 64 output channels
  fe_main<<<grid, 256, 0, stream>>>(x, k, Ec, Ps, bias, coef, out);
}

// Round 7
// 30.286 us; speedup vs baseline: 1.1673x; 1.0395x over previous
//
#include <hip/hip_runtime.h>

// out[b,o] = sum_{i,n} (Ps*tanh(k*(x + Ec*bm)) + bias) * coef
// bm = 1 + ch*sg; ch = -0.4*sigmoid(-10*(x-prev)); sg = sigmoid(-10*(x+Ec))
// tanh(a) = 1 - 2*r, r = rcp(1+exp2(TANH_C*k*inner))
// out = base[o] - 2 * sum pc*r,  base[o] = sum (bias*coef + pc)
//
// R7: skeleton change. All six prior rounds shared: per-block 2KB-stride
// param gather (10.5M redundant loads), per-term b128 param LDS reads,
// ~31% occupancy. fe_prep packs params/xch into d_ws ONCE (coalesced);
// fe_main holds params in 16 VGPRs (coalesced b128 loads), 8 NAMED
// accumulators (rule #20 safe), main-loop LDS = one conflict-free b64
// broadcast per term. LDS 9.3KB, ~70 VGPR -> 6 blocks/CU.

#define GATE_C 14.426950408889634f   // 10*log2(e)
#define TANH_C 2.8853900817779268f   // 2*log2(e)

constexpr int B = 512, I = 128, O = 64, NB = 8, BT = 8;
constexpr size_t PK_OFF  = 0;                      // float4 [o][i][n]  1 MB
constexpr size_t PB_OFF  = (size_t)O * I * NB * 16;        // float, 256 KB
constexpr size_t XCH_OFF = PB_OFF + (size_t)O * I * NB * 4; // float2, 512 KB
constexpr size_t WS_NEED = XCH_OFF + (size_t)B * I * 8;

__device__ __forceinline__ float sig_neg(float u) {  // sigmoid(-10*u/GATE...)
  return __builtin_amdgcn_rcpf(1.f + __builtin_amdgcn_exp2f(u));
}

// ---------------- phase 1: pack params + x-features once ----------------
__global__ __launch_bounds__(256) void fe_prep(
    const float* __restrict__ x, const float* __restrict__ k,
    const float* __restrict__ Ec, const float* __restrict__ Ps,
    const float* __restrict__ bias, const float* __restrict__ coef,
    float4* __restrict__ pk, float* __restrict__ pb, float2* __restrict__ xch)
{
  const int idx = blockIdx.x * 256 + threadIdx.x;    // 0..65535
  // params: pk[o][i][n]
  const int o = idx >> 10, i = (idx >> 3) & 127, n = idx & 7;
  const int g = (i * O + o) * NB + n;
  const float E = Ec[g], K = k[g], P = Ps[g], C = coef[g], Bs = bias[g];
  const float pc = P * C;
  pk[idx] = make_float4(E, E * GATE_C, K * TANH_C, pc);
  pb[idx] = fmaf(Bs, C, pc);
  // x features: xch[b][i], idx = b*I + i (coalesced)
  const float xv = x[idx];
  const float pv = (idx < I) ? 0.f : x[idx - I];
  const float ch = -0.4f * sig_neg(GATE_C * (xv - pv));
  xch[idx] = make_float2(xv, ch);
}

// ---------------- phase 2: main ----------------
#define TERM(ACC, BL, S) {                                                  \
    const float2 xc = xl[BL][i0 + 32 * (S)];                                \
    const float sg = sig_neg(fmaf(xc.x, GATE_C, pr##S.y));                  \
    const float bm = fmaf(xc.y, sg, 1.f);                                   \
    const float inner = fmaf(pr##S.x, bm, xc.x);                            \
    const float r = sig_neg(pr##S.z * inner);                               \
    ACC = fmaf(pr##S.w, r, ACC); }

#define ROW(ACC, BL) TERM(ACC, BL, 0) TERM(ACC, BL, 1) \
                     TERM(ACC, BL, 2) TERM(ACC, BL, 3)

#define NRED(ACC, BL) { float t = ACC;                                      \
    t += __shfl_xor(t, 1); t += __shfl_xor(t, 2); t += __shfl_xor(t, 4);    \
    if (n == 0) racc[BL][i0] = t; }

__global__ __launch_bounds__(256, 6) void fe_main(
    const float4* __restrict__ pk, const float* __restrict__ pb,
    const float2* __restrict__ xch, float* __restrict__ out)
{
  __shared__ float2 xl[BT][I];      // 8 KB, conflict-free both ways
  __shared__ float racc[BT][33];    // 1 KB (+pad)
  __shared__ float red[4];

  const int tid = threadIdx.x;
  const int o  = blockIdx.y;
  const int b0 = blockIdx.x * BT;
  const int i0 = tid >> 3, n = tid & 7;

  // params -> 16 VGPRs, fully coalesced b128 loads
  const int pbase_idx = (o * I + i0) * NB + n;
  const float4 pr0 = pk[pbase_idx];
  const float4 pr1 = pk[pbase_idx + 32 * NB];
  const float4 pr2 = pk[pbase_idx + 64 * NB];
  const float4 pr3 = pk[pbase_idx + 96 * NB];
  float pbase = pb[pbase_idx]            + pb[pbase_idx + 32 * NB]
              + pb[pbase_idx + 64 * NB]  + pb[pbase_idx + 96 * NB];

  // stage {x, ch} tile: 1024 float2, coalesced
  for (int e = tid; e < BT * I; e += 256)
    xl[e >> 7][e & 127] = xch[b0 * I + e];

  // base[o]: wave butterfly -> red[wave]
  #pragma unroll
  for (int m = 1; m < 64; m <<= 1) pbase += __shfl_xor(pbase, m);
  if ((tid & 63) == 0) red[tid >> 6] = pbase;
  __syncthreads();

  float a0 = 0.f, a1 = 0.f, a2 = 0.f, a3 = 0.f,
        a4 = 0.f, a5 = 0.f, a6 = 0.f, a7 = 0.f;
  ROW(a0, 0) ROW(a1, 1) ROW(a2, 2) ROW(a3, 3)
  ROW(a4, 4) ROW(a5, 5) ROW(a6, 6) ROW(a7, 7)

  NRED(a0, 0) NRED(a1, 1) NRED(a2, 2) NRED(a3, 3)
  NRED(a4, 4) NRED(a5, 5) NRED(a6, 6) NRED(a7, 7)
  __syncthreads();

  // final: thread (bl = tid>>5, q = tid&31) reduces 32 i0-partials
  const int bl = tid >> 5, q = tid & 31;
  float v = racc[bl][q];
  v += __shfl_xor(v, 1);
  v += __shfl_xor(v, 2);
  v += __shfl_xor(v, 4);
  v += __shfl_xor(v, 8);
  v += __shfl_xor(v, 16);
  if (q == 0) {
    const float base = red[0] + red[1] + red[2] + red[3];
    out[(b0 + bl) * O + o] = fmaf(-2.f, v, base);
  }
}

// ---------------- fallback (R1 kernel, used only if ws too small) --------
__global__ __launch_bounds__(256) void fe_fb(
    const float* __restrict__ x, const float* __restrict__ k,
    const float* __restrict__ Ec, const float* __restrict__ Ps,
    const float* __restrict__ bias, const float* __restrict__ coef,
    float* __restrict__ out)
{
  __shared__ float4 p_lds[I * NB];
  __shared__ float2 xc_lds[32][I + 1];
  __shared__ float red[4];
  const int tid = threadIdx.x, o = blockIdx.y, b0 = blockIdx.x * 32;
  float pbase = 0.f;
  for (int e = tid; e < I * NB; e += 256) {
    const int i = e >> 3, nn = e & 7;
    const int g = (i * O + o) * NB + nn;
    const float E = Ec[g], K = k[g], P = Ps[g], C = coef[g], Bs = bias[g];
    const float pc = P * C;
    p_lds[e] = make_float4(E, E * GATE_C, K * TANH_C, pc);
    pbase += fmaf(Bs, C, pc);
  }
  for (int e = tid; e < 32 * I; e += 256) {
    const int bl = e >> 7, i = e & 127;
    const int bg = b0 + bl;
    const float xv = x[bg * I + i];
    const float pv = (bg == 0) ? 0.f : x[(bg - 1) * I + i];
    const float c = -0.4f * sig_neg(GATE_C * (xv - pv));
    xc_lds[bl][i] = make_float2(xv, c);
  }
  #pragma unroll
  for (int m = 1; m < 64; m <<= 1) pbase += __shfl_xor(pbase, m);
  if ((tid & 63) == 0) red[tid >> 6] = pbase;
  __syncthreads();
  const int bl = tid >> 3, n = tid & 7;
  const float4* __restrict__ prow = p_lds + n;
  const float2* __restrict__ xrow = &xc_lds[bl][0];
  float acc = 0.f;
  #pragma unroll 4
  for (int i = 0; i < I; ++i) {
    const float2 xc = xrow[i];
    const float4 p  = prow[i * 8];
    const float sg = sig_neg(fmaf(xc.x, GATE_C, p.y));
    const float bm = fmaf(xc.y, sg, 1.f);
    const float inner = fmaf(p.x, bm, xc.x);
    const float r = sig_neg(p.z * inner);
    acc = fmaf(p.w, r, acc);
  }
  acc += __shfl_xor(acc, 1);
  acc += __shfl_xor(acc, 2);
  acc += __shfl_xor(acc, 4);
  if (n == 0) {
    const float base = red[0] + red[1] + red[2] + red[3];
    out[(b0 + bl) * O + o] = fmaf(-2.f, acc, base);
  }
}

extern "C" void kernel_launch(void* const* d_in, const int* in_sizes, int n_in,
                              void* d_out, int out_size, void* d_ws, size_t ws_size,
                              hipStream_t stream) {
  const float* x    = (const float*)d_in[0];
  const float* k    = (const float*)d_in[1];
  const float* Ec   = (const float*)d_in[2];
  const float* Ps   = (const float*)d_in[3];
  const float* bias = (const float*)d_in[4];
  const float* coef = (const float*)d_in[5];
  float* out = (float*)d_out;

  if (ws_size >= WS_NEED) {
    float4* pk  = (float4*)((char*)d_ws + PK_OFF);
    float*  pb  = (float*) ((char*)d_ws + PB_OFF);
    float2* xch = (float2*)((char*)d_ws + XCH_OFF);
    fe_prep<<<dim3(O * I * NB / 256), 256, 0, stream>>>(x, k, Ec, Ps, bias, coef,
                                                        pk, pb, xch);
    dim3 grid(B / BT, O);   // 64 x 64
    fe_main<<<grid, 256, 0, stream>>>(pk, pb, xch, out);
  } else {
    dim3 grid(B / 32, O);
    fe_fb<<<grid, 256, 0, stream>>>(x, k, Ec, Ps, bias, coef, out);
  }
}

// Round 8
// 25.820 us; speedup vs baseline: 1.3693x; 1.1730x over previous
//
#include <hip/hip_runtime.h>

// out[b,o] = sum_{i,n} (Ps*tanh(k*(x + Ec*bm)) + bias) * coef
// bm = 1 + c*sg; c = -0.4*sigmoid(-10*(x-prev)); sg = sigmoid(-10*(x+Ec))
// tanh(a) = 1 - 2*r, r = rcp(1+exp2(TANH_C*k*inner))
// out = base[o] - 2 * sum pc*r,  base[o] = sum (bias*coef + pc)
//
// R8: A/B vs R1 -- IDENTICAL main-loop body, persistent-block structure.
// 1024-thread blocks (16 waves), grid (8,64)=512 blocks; each block stages
// params for its o ONCE, then processes 2 b-tiles of 32. Tests whether the
// ~28us wall is per-block prologue/dispatch/occupancy (expect 19-23us) or
// the loop body itself (expect ~28us; then R9 cuts trans 4->3 via paired
// rcp). Thread map: n=tid&7, ih=(tid>>3)&3, bl=tid>>5; reductions via
// shfl_xor 1,2,4 (n) + 8,16 (ih), writers at tid&31==0.

#define GATE_C 14.426950408889634f   // 10*log2(e)
#define TANH_C 2.8853900817779268f   // 2*log2(e)

constexpr int B = 512, I = 128, O = 64, NB = 8, BT = 32, TILES = 2;

__device__ __forceinline__ float sig_neg(float u) {
  return __builtin_amdgcn_rcpf(1.f + __builtin_amdgcn_exp2f(u));
}

__global__ __launch_bounds__(1024, 4) void fe_main(
    const float* __restrict__ x, const float* __restrict__ k,
    const float* __restrict__ Ec, const float* __restrict__ Ps,
    const float* __restrict__ bias, const float* __restrict__ coef,
    float* __restrict__ out)
{
  __shared__ float4 p_lds[I * NB];        // 16 KB: {Ec, Ec*G, k*T, Ps*coef}
  __shared__ float2 xc_lds[BT][I + 1];    // 33 KB: {x, c}, +1 pad
  __shared__ float red[16];

  const int tid = threadIdx.x;
  const int o = blockIdx.y;
  const int bbase = blockIdx.x * (BT * TILES);

  // ---- params for this o: staged ONCE per block (1 elem/thread) ----
  {
    const int i = tid >> 3, nn = tid & 7;
    const int g = (i * O + o) * NB + nn;
    const float E = Ec[g], K = k[g], P = Ps[g], C = coef[g], Bs = bias[g];
    const float pc = P * C;
    p_lds[tid] = make_float4(E, E * GATE_C, K * TANH_C, pc);
    float pbase = fmaf(Bs, C, pc);
    #pragma unroll
    for (int m = 1; m < 64; m <<= 1) pbase += __shfl_xor(pbase, m);
    if ((tid & 63) == 0) red[tid >> 6] = pbase;
  }

  const int n  = tid & 7;
  const int ih = (tid >> 3) & 3;          // i-quarter: 32 i's each
  const int bl = tid >> 5;                // 0..31 batch row in tile
  const float4* __restrict__ prow = p_lds + (ih * 32) * 8 + n;

  for (int t = 0; t < TILES; ++t) {
    const int b0 = bbase + t * BT;
    __syncthreads();   // xc_lds safe to overwrite (and red ready at t=0)

    // stage {x, c} for this tile: 4096 float2 / 1024 threads, coalesced
    for (int e = tid; e < BT * I; e += 1024) {
      const int xbl = e >> 7, xi = e & 127;
      const int bg = b0 + xbl;
      const float xv = x[bg * I + xi];
      const float pv = (bg == 0) ? 0.f : x[(bg - 1) * I + xi];
      const float c = -0.4f * sig_neg(GATE_C * (xv - pv));
      xc_lds[xbl][xi] = make_float2(xv, c);
    }
    __syncthreads();

    // ---- main loop: EXACT R1 body, 32 i's per thread ----
    const float2* __restrict__ xrow = &xc_lds[bl][ih * 32];
    float acc = 0.f;
    #pragma unroll 4
    for (int it = 0; it < 32; ++it) {
      const float2 xc = xrow[it];
      const float4 p  = prow[it * 8];
      const float sg = sig_neg(fmaf(xc.x, GATE_C, p.y));   // sigmoid(-10(x+Ec))
      const float bm = fmaf(xc.y, sg, 1.f);                // 1 + c*sg
      const float inner = fmaf(p.x, bm, xc.x);             // x + Ec*bm
      const float r = sig_neg(p.z * inner);                // rcp(1+exp(2a))
      acc = fmaf(p.w, r, acc);                             // += pc*r
    }

    // reduce over n (1,2,4) then ih (8,16); writers: tid&31 == 0
    acc += __shfl_xor(acc, 1);
    acc += __shfl_xor(acc, 2);
    acc += __shfl_xor(acc, 4);
    acc += __shfl_xor(acc, 8);
    acc += __shfl_xor(acc, 16);

    if ((tid & 31) == 0) {
      float base = 0.f;
      #pragma unroll
      for (int w = 0; w < 16; ++w) base += red[w];
      out[(b0 + bl) * O + o] = fmaf(-2.f, acc, base);
    }
  }
}

extern "C" void kernel_launch(void* const* d_in, const int* in_sizes, int n_in,
                              void* d_out, int out_size, void* d_ws, size_t ws_size,
                              hipStream_t stream) {
  const float* x    = (const float*)d_in[0];
  const float* k    = (const float*)d_in[1];
  const float* Ec   = (const float*)d_in[2];
  const float* Ps   = (const float*)d_in[3];
  const float* bias = (const float*)d_in[4];
  const float* coef = (const float*)d_in[5];
  float* out = (float*)d_out;

  dim3 grid(B / (BT * TILES), O);   // (8, 64) = 512 persistent-ish blocks
  fe_main<<<grid, 1024, 0, stream>>>(x, k, Ec, Ps, bias, coef, out);
}